// Round 3
// baseline (378.753 us; speedup 1.0000x reference)
//
#include <hip/hip_runtime.h>

// LinearQuant: out[32,8192] = x[32,8192] @ (int8-valued-int32 W[8192,8192] * scaler)
// Memory-bound: 256 MiB weight stream read exactly once; floor ~40 us @ ~6.7 TB/s.
//
// R2 changes vs R1 (375 us):
//   - x values broadcast from LDS (8x ds_read_b128/k, uniform addr = broadcast),
//     NOT per-lane global loads (R1's uniform->s_load bet likely failed under
//     alias analysis with atomics in the kernel).
//   - no atomics: K-split partials to d_ws + deterministic reduce kernel.
//   - no d_out memset needed anymore.
// (R3 = R2 resubmitted: the R2 bench died in GPU acquisition, never ran.)

#define IN_F   8192
#define OUT_F  8192
#define BATCH  32
#define KSPLIT 32
#define KCHUNK (IN_F / KSPLIT)   // 256 rows of W per block

// xt[k][b] = x[b][k] * scaler   (k-major so a block's chunk is contiguous)
__global__ void prep_x_kernel(const float* __restrict__ x,
                              const float* __restrict__ scaler,
                              float* __restrict__ xt) {
    int i = blockIdx.x * 256 + threadIdx.x;   // 0 .. BATCH*IN_F-1
    int k = i >> 5;
    int b = i & 31;
    xt[i] = x[b * IN_F + k] * scaler[0];      // 1 MiB total, L2 absorbs strided reads
}

__global__ __launch_bounds__(256, 4)
void lq_main_kernel(const int* __restrict__ w,
                    const float* __restrict__ xt,
                    float* __restrict__ part) {
    __shared__ float4 xs[KCHUNK * (BATCH / 4)];       // 32 KB: whole k-chunk of x
    const int tid = threadIdx.x;
    const int col = blockIdx.x * 256 + tid;           // output column (lane-coalesced)
    const int kc  = blockIdx.y;
    const int k0  = kc * KCHUNK;

    // Stage x chunk once per block: 2048 float4, 256 threads -> 8 each, coalesced.
    const float4* xg = (const float4*)(xt + (size_t)k0 * BATCH);
#pragma unroll
    for (int j = 0; j < (KCHUNK * BATCH / 4) / 256; ++j)
        xs[j * 256 + tid] = xg[j * 256 + tid];
    __syncthreads();

    float acc[BATCH];
#pragma unroll
    for (int b = 0; b < BATCH; ++b) acc[b] = 0.0f;

    const int* wp = w + (size_t)k0 * OUT_F + col;

#pragma unroll 8
    for (int k = 0; k < KCHUNK; ++k) {
        float wv = (float)wp[(size_t)k * OUT_F];      // 1 coalesced dword/lane (256 B/wave)
        const float4* xk = &xs[k * (BATCH / 4)];
#pragma unroll
        for (int q = 0; q < BATCH / 4; ++q) {         // 8x ds_read_b128, broadcast
            float4 xv = xk[q];
            acc[4 * q + 0] = fmaf(xv.x, wv, acc[4 * q + 0]);
            acc[4 * q + 1] = fmaf(xv.y, wv, acc[4 * q + 1]);
            acc[4 * q + 2] = fmaf(xv.z, wv, acc[4 * q + 2]);
            acc[4 * q + 3] = fmaf(xv.w, wv, acc[4 * q + 3]);
        }
    }

    // Write this K-chunk's partial result: part[kc][b][col]
    float* pp = part + (size_t)kc * (BATCH * OUT_F) + col;
#pragma unroll
    for (int b = 0; b < BATCH; ++b)
        pp[(size_t)b * OUT_F] = acc[b];
}

// out[i] = sum_c part[c][i]   (deterministic order, coalesced per c)
__global__ void reduce_kernel(const float* __restrict__ part,
                              float* __restrict__ out) {
    int i = blockIdx.x * 256 + threadIdx.x;           // over BATCH*OUT_F
    float s = 0.0f;
#pragma unroll
    for (int c = 0; c < KSPLIT; ++c)
        s += part[(size_t)c * (BATCH * OUT_F) + i];
    out[i] = s;
}

extern "C" void kernel_launch(void* const* d_in, const int* in_sizes, int n_in,
                              void* d_out, int out_size, void* d_ws, size_t ws_size,
                              hipStream_t stream) {
    const float* x = (const float*)d_in[0];
    const int*   w = (const int*)d_in[1];
    const float* s = (const float*)d_in[2];
    float* out  = (float*)d_out;
    float* xt   = (float*)d_ws;                               // 1 MiB
    float* part = (float*)d_ws + (size_t)BATCH * IN_F;        // 32 MiB

    prep_x_kernel<<<dim3((BATCH * IN_F) / 256), dim3(256), 0, stream>>>(x, s, xt);

    lq_main_kernel<<<dim3(OUT_F / 256, KSPLIT), dim3(256), 0, stream>>>(w, xt, part);

    reduce_kernel<<<dim3((BATCH * OUT_F) / 256), dim3(256), 0, stream>>>(part, out);
}